// Round 3
// baseline (471.401 us; speedup 1.0000x reference)
//
#include <hip/hip_runtime.h>
#include <float.h>

#define PROMPT_LEN 2048
#define VOCAB 49408
#define DIM 768
#define ROWS_TOTAL (VOCAB + PROMPT_LEN)   // 51456
#define MT 2                               // prompts per refine block
#define EPS 0.02f                          // fp32 ambiguity margin (~20x error bound)

// ws layout:
//   [0, VOCAB*4)                 : c_sq  (float per vocab row)
//   [VOCAB*4, VOCAB*8)           : candidate indices (int)
//   [VOCAB*8, +PROMPT_LEN*4)     : p_sq  (float per prompt row)
//   [... + 12]                   : scalars: [0]=count, [1]=cmin bits, [2]=pmax_sq bits

__global__ void k_init(unsigned* scal) {
    if (threadIdx.x == 0) {
        scal[0] = 0u;
        scal[1] = 0x7F800000u;   // +inf
        scal[2] = 0u;            // 0
    }
}

// 8 contiguous rows per wave, 2-row unroll (6 loads in flight). 1608 blocks.
__global__ void __launch_bounds__(256) k_sumsq(const float* __restrict__ prompt,
                                               const float* __restrict__ clip,
                                               float* __restrict__ csq,
                                               float* __restrict__ psq) {
    int wid  = threadIdx.x >> 6;
    int lane = threadIdx.x & 63;
    int base = blockIdx.x * 32 + wid * 8;      // 1608*32 == 51456 exactly

    for (int r = base; r < base + 8; r += 2) {
        const float* s0 = (r     < VOCAB) ? clip + (size_t)r * DIM
                                          : prompt + (size_t)(r - VOCAB) * DIM;
        const float* s1 = (r + 1 < VOCAB) ? clip + (size_t)(r + 1) * DIM
                                          : prompt + (size_t)(r + 1 - VOCAB) * DIM;
        float4 a0 = ((const float4*)s0)[lane];
        float4 a1 = ((const float4*)s0)[64 + lane];
        float4 a2 = ((const float4*)s0)[128 + lane];
        float4 b0 = ((const float4*)s1)[lane];
        float4 b1 = ((const float4*)s1)[64 + lane];
        float4 b2 = ((const float4*)s1)[128 + lane];
        float sA = a0.x*a0.x + a0.y*a0.y + a0.z*a0.z + a0.w*a0.w
                 + a1.x*a1.x + a1.y*a1.y + a1.z*a1.z + a1.w*a1.w
                 + a2.x*a2.x + a2.y*a2.y + a2.z*a2.z + a2.w*a2.w;
        float sB = b0.x*b0.x + b0.y*b0.y + b0.z*b0.z + b0.w*b0.w
                 + b1.x*b1.x + b1.y*b1.y + b1.z*b1.z + b1.w*b1.w
                 + b2.x*b2.x + b2.y*b2.y + b2.z*b2.z + b2.w*b2.w;
        #pragma unroll
        for (int m = 32; m >= 1; m >>= 1) {
            sA += __shfl_xor(sA, m, 64);
            sB += __shfl_xor(sB, m, 64);
        }
        if (lane == 0) {
            if (r < VOCAB) csq[r] = sA; else psq[r - VOCAB] = sA;
            if (r + 1 < VOCAB) csq[r + 1] = sB; else psq[r + 1 - VOCAB] = sB;
        }
    }
}

// cmin over csq, pmax over psq. 64 blocks -> 128 atomics total.
__global__ void __launch_bounds__(256) k_reduce(const float* __restrict__ csq,
                                                const float* __restrict__ psq,
                                                unsigned* __restrict__ scal) {
    int tid = blockIdx.x * 256 + threadIdx.x;
    const int stride = 64 * 256;
    float mn = 1e30f, mx = 0.f;
    for (int i = tid; i < VOCAB; i += stride)      mn = fminf(mn, csq[i]);
    for (int i = tid; i < PROMPT_LEN; i += stride) mx = fmaxf(mx, psq[i]);
    #pragma unroll
    for (int m = 32; m >= 1; m >>= 1) {
        mn = fminf(mn, __shfl_xor(mn, m, 64));
        mx = fmaxf(mx, __shfl_xor(mx, m, 64));
    }
    __shared__ float smn[4], smx[4];
    int wid = threadIdx.x >> 6, lane = threadIdx.x & 63;
    if (lane == 0) { smn[wid] = mn; smx[wid] = mx; }
    __syncthreads();
    if (threadIdx.x == 0) {
        mn = fminf(fminf(smn[0], smn[1]), fminf(smn[2], smn[3]));
        mx = fmaxf(fmaxf(smx[0], smx[1]), fmaxf(smx[2], smx[3]));
        atomicMin(&scal[1], __float_as_uint(mn));
        atomicMax(&scal[2], __float_as_uint(mx));
    }
}

// Keep v iff c_sq[v] - 2B*sqrt(c_sq[v]) <= min_u (c_sq[u] + 2B*sqrt(c_sq[u])).
__global__ void k_compact(const float* __restrict__ csq, int* __restrict__ cand,
                          unsigned* __restrict__ scal) {
    float cmin    = __uint_as_float(scal[1]);
    float pmax_sq = __uint_as_float(scal[2]);
    float B  = sqrtf(pmax_sq) * 1.0001f + 1e-6f;
    float U  = cmin + 2.f * B * sqrtf(cmin) + 1.0f;
    float sT = B + sqrtf(B * B + U);
    float T  = sT * sT;
    int v = blockIdx.x * blockDim.x + threadIdx.x;
    if (v < VOCAB && csq[v] <= T) {
        int pos = atomicAdd((int*)&scal[0], 1);
        cand[pos] = v;
    }
}

// One block per MT prompts. fp32 scan of d2' = csq[v] - 2*p.c (p_sq cancels in argmin),
// best + runner-up tracked; if gap < EPS, exact fp64 rescan (R2-validated path).
__global__ void __launch_bounds__(256) k_refine(const float* __restrict__ prompt,
                                                const float* __restrict__ clip,
                                                const float* __restrict__ csq,
                                                const int* __restrict__ cand,
                                                const unsigned* __restrict__ scal,
                                                float* __restrict__ out) {
    int wid  = threadIdx.x >> 6;
    int lane = threadIdx.x & 63;
    int m0 = blockIdx.x * MT;
    int count = (int)scal[0];

    float pf[MT][12];
    #pragma unroll
    for (int t = 0; t < MT; ++t) {
        const float* prow = prompt + (size_t)(m0 + t) * DIM;
        #pragma unroll
        for (int i = 0; i < 3; ++i) {
            float4 v = ((const float4*)prow)[i * 64 + lane];
            pf[t][i*4+0] = v.x; pf[t][i*4+1] = v.y;
            pf[t][i*4+2] = v.z; pf[t][i*4+3] = v.w;
        }
    }

    float b1[MT], b2[MT];
    int   bi[MT];
    #pragma unroll
    for (int t = 0; t < MT; ++t) { b1[t] = FLT_MAX; b2[t] = FLT_MAX; bi[t] = 0x7fffffff; }

    for (int ci = wid; ci < count; ci += 4) {
        int v = cand[ci];
        float cs = csq[v];
        const float* crow = clip + (size_t)v * DIM;
        float s[MT];
        #pragma unroll
        for (int t = 0; t < MT; ++t) s[t] = 0.f;
        #pragma unroll
        for (int i = 0; i < 3; ++i) {
            float4 c = ((const float4*)crow)[i * 64 + lane];
            #pragma unroll
            for (int t = 0; t < MT; ++t) {
                s[t] = fmaf(c.x, pf[t][i*4+0], s[t]);
                s[t] = fmaf(c.y, pf[t][i*4+1], s[t]);
                s[t] = fmaf(c.z, pf[t][i*4+2], s[t]);
                s[t] = fmaf(c.w, pf[t][i*4+3], s[t]);
            }
        }
        #pragma unroll
        for (int msk = 32; msk >= 1; msk >>= 1) {
            #pragma unroll
            for (int t = 0; t < MT; ++t) s[t] += __shfl_xor(s[t], msk, 64);
        }
        #pragma unroll
        for (int t = 0; t < MT; ++t) {
            float d2 = fmaf(-2.f, s[t], cs);
            if (d2 < b1[t]) { b2[t] = b1[t]; b1[t] = d2; bi[t] = v; }
            else if (d2 < b2[t]) b2[t] = d2;
            else if (d2 == b1[t]) b2[t] = d2;   // exact tie -> force fallback
        }
    }

    // cross-wave merge
    __shared__ float sb1[4][MT], sb2[4][MT];
    __shared__ int   sbi[4][MT];
    __shared__ int   sWin[MT];
    __shared__ int   sNeed[MT];
    if (lane == 0) {
        #pragma unroll
        for (int t = 0; t < MT; ++t) { sb1[wid][t] = b1[t]; sb2[wid][t] = b2[t]; sbi[wid][t] = bi[t]; }
    }
    __syncthreads();
    if (threadIdx.x < MT) {
        int t = threadIdx.x;
        float gb1 = FLT_MAX, gb2 = FLT_MAX;
        int gbi = 0x7fffffff;
        for (int w = 0; w < 4; ++w) {
            float w1 = sb1[w][t], w2 = sb2[w][t];
            int   wi = sbi[w][t];
            if (w1 < gb1 || (w1 == gb1 && wi < gbi)) {
                gb2 = fminf(fminf(gb2, gb1), w2);
                gb1 = w1; gbi = wi;
            } else {
                gb2 = fminf(gb2, fminf(w1, w2));
            }
        }
        sWin[t]  = gbi;
        sNeed[t] = (gb2 - gb1 < EPS) ? 1 : 0;
    }
    __syncthreads();

    // exact fp64 fallback for ambiguous prompts (rare)
    for (int t = 0; t < MT; ++t) {
        if (!sNeed[t]) continue;
        double pd[12];
        #pragma unroll
        for (int j = 0; j < 12; ++j) pd[j] = (double)pf[t][j];
        double best = 1e300;
        int bestIdx = 0x7fffffff;
        for (int ci = wid; ci < count; ci += 4) {
            int v = cand[ci];
            const float* crow = clip + (size_t)v * DIM;
            double s = 0.0;
            #pragma unroll
            for (int i = 0; i < 3; ++i) {
                float4 c = ((const float4*)crow)[i * 64 + lane];
                double d0 = (double)c.x - pd[i*4+0];
                double d1 = (double)c.y - pd[i*4+1];
                double d2 = (double)c.z - pd[i*4+2];
                double d3 = (double)c.w - pd[i*4+3];
                s = fma(d0, d0, s); s = fma(d1, d1, s);
                s = fma(d2, d2, s); s = fma(d3, d3, s);
            }
            #pragma unroll
            for (int msk = 32; msk >= 1; msk >>= 1) s += __shfl_xor(s, msk, 64);
            if (s < best || (s == best && v < bestIdx)) { best = s; bestIdx = v; }
        }
        __shared__ double fB[4];
        __shared__ int    fI[4];
        if (lane == 0) { fB[wid] = best; fI[wid] = bestIdx; }
        __syncthreads();
        if (threadIdx.x == 0) {
            double b = fB[0]; int bi2 = fI[0];
            #pragma unroll
            for (int w = 1; w < 4; ++w)
                if (fB[w] < b || (fB[w] == b && fI[w] < bi2)) { b = fB[w]; bi2 = fI[w]; }
            sWin[t] = bi2;
        }
        __syncthreads();
    }

    // epilogue: out = (c - p) + p in fp32, plus id as float
    #pragma unroll
    for (int t = 0; t < MT; ++t) {
        int win = sWin[t];
        int m = m0 + t;
        if (threadIdx.x < 192) {
            float4 c = ((const float4*)(clip + (size_t)win * DIM))[threadIdx.x];
            float4 p = ((const float4*)(prompt + (size_t)m * DIM))[threadIdx.x];
            float4 o;
            o.x = (c.x - p.x) + p.x;
            o.y = (c.y - p.y) + p.y;
            o.z = (c.z - p.z) + p.z;
            o.w = (c.w - p.w) + p.w;
            ((float4*)(out + (size_t)m * DIM))[threadIdx.x] = o;
        }
        if (threadIdx.x == 0) out[(size_t)PROMPT_LEN * DIM + m] = (float)win;
    }
}

extern "C" void kernel_launch(void* const* d_in, const int* in_sizes, int n_in,
                              void* d_out, int out_size, void* d_ws, size_t ws_size,
                              hipStream_t stream) {
    const float* prompt = (const float*)d_in[0];
    const float* clip   = (const float*)d_in[1];
    float* out = (float*)d_out;

    float*    csq  = (float*)d_ws;
    int*      cand = (int*)((char*)d_ws + (size_t)VOCAB * 4);
    float*    psq  = (float*)((char*)d_ws + (size_t)VOCAB * 8);
    unsigned* scal = (unsigned*)((char*)d_ws + (size_t)VOCAB * 8 + (size_t)PROMPT_LEN * 4);

    k_init<<<1, 64, 0, stream>>>(scal);
    k_sumsq<<<ROWS_TOTAL / 32, 256, 0, stream>>>(prompt, clip, csq, psq);
    k_reduce<<<64, 256, 0, stream>>>(csq, psq, scal);
    k_compact<<<(VOCAB + 255) / 256, 256, 0, stream>>>(csq, cand, scal);
    k_refine<<<PROMPT_LEN / MT, 256, 0, stream>>>(prompt, clip, csq, cand, scal, out);
}